// Round 1
// baseline (1088.906 us; speedup 1.0000x reference)
//
#include <hip/hip_runtime.h>

// Problem: ShortTermInterestExtractor — GRU(64->64, T=200, B=4096) + attention + AUGRU.
// Strategy: MFMA 16x16x32 bf16 with hi/lo split (3-term) for fp32-grade precision.
// Weights resident in registers as A-fragments; h exchanged via double-buffered LDS.

#define Bq   4096
#define Tq   200
#define HIDq 64
#define BT   8      // batch elements per block (16-wide MFMA N dim half-used -> 512 blocks for occupancy)

typedef __attribute__((ext_vector_type(8))) short short8;  // 8 bf16 in 4 VGPRs
typedef __attribute__((ext_vector_type(4))) float f32x4;

#define MFMA(a, b, c) __builtin_amdgcn_mfma_f32_16x16x32_bf16((a), (b), (c), 0, 0, 0)

__device__ __forceinline__ unsigned short f2bf(float f) {  // RNE float->bf16 bits
  unsigned int u = __float_as_uint(f);
  u += 0x7fffu + ((u >> 16) & 1u);
  return (unsigned short)(u >> 16);
}
__device__ __forceinline__ float bf2f(unsigned short h) {
  return __uint_as_float(((unsigned int)h) << 16);
}
__device__ __forceinline__ float sigm(float x) { return 1.0f / (1.0f + __expf(-x)); }

// Split 8 fp32 (two f32x4) into bf16 hi + bf16 lo fragments.
__device__ __forceinline__ void split8(f32x4 a, f32x4 b, short8 &hi, short8 &lo) {
#pragma unroll
  for (int i = 0; i < 4; ++i) {
    unsigned short h = f2bf(a[i]);
    hi[i] = (short)h;
    lo[i] = (short)f2bf(a[i] - bf2f(h));
  }
#pragma unroll
  for (int i = 0; i < 4; ++i) {
    unsigned short h = f2bf(b[i]);
    hi[i + 4] = (short)h;
    lo[i + 4] = (short)f2bf(b[i] - bf2f(h));
  }
}

// ---------------------------------------------------------------------------
// Kernel 1: GRU forward over T steps + fused attention scores.
// Block: 256 thr (4 waves). Wave w owns hidden slice jh = 16*w.
// Per MFMA tile: C[j_local][b_local], A = weight rows (M=16 j), B = x^T / h^T.
// C layout (m89-verified): col = lane&15 (=b), row = (lane>>4)*4 + reg (=j).
// A/B frag: "16-dim" = lane&15, k = (lane>>4)*8 + e (k-permutation cancels A vs B).
// ---------------------------------------------------------------------------
__global__ __launch_bounds__(256, 2)
void gru_fwd(const float* __restrict__ x, const float* __restrict__ pq,
             const int* __restrict__ lengths,
             const float* __restrict__ Wih, const float* __restrict__ Whh,
             const float* __restrict__ bih, const float* __restrict__ bhh,
             unsigned short* __restrict__ outbf,   // [T][B][64] bf16
             float* __restrict__ scores)           // [B][T] fp32
{
  __shared__ alignas(16) unsigned short hb_hi[2][16][72];  // h tile, bf16 hi, padded rows
  __shared__ alignas(16) unsigned short hb_lo[2][16][72];  // h tile, bf16 lo
  __shared__ float slds[2][4][8];                          // per-wave score partials

  const int tid  = threadIdx.x;
  const int w    = tid >> 6;        // wave 0..3
  const int lane = tid & 63;
  const int c    = lane & 15;       // A row (j within tile) AND B col (b within tile)
  const int g    = lane >> 4;       // k-octet / C row group
  const int bl   = c & (BT - 1);    // clamp batch col: cols 8..15 duplicate 0..7
  const int b    = blockIdx.x * BT + bl;
  const int jh   = w * 16;

  for (int i = tid; i < 2 * 16 * 72; i += 256) {
    ((unsigned short*)hb_hi)[i] = 0;
    ((unsigned short*)hb_lo)[i] = 0;
  }

  // Weight A-fragments, resident hi/lo. Row m = c -> global j row = gate*64 + jh + c.
  short8 wiH[3][2], wiL[3][2], whH[3][2], whL[3][2];
#pragma unroll
  for (int gt = 0; gt < 3; ++gt)
#pragma unroll
    for (int kc = 0; kc < 2; ++kc) {
      const float* p = Wih + (size_t)(gt * 64 + jh + c) * 64 + kc * 32 + g * 8;
      split8(*(const f32x4*)p, *(const f32x4*)(p + 4), wiH[gt][kc], wiL[gt][kc]);
      const float* q = Whh + (size_t)(gt * 64 + jh + c) * 64 + kc * 32 + g * 8;
      split8(*(const f32x4*)q, *(const f32x4*)(q + 4), whH[gt][kc], whL[gt][kc]);
    }

  // Biases along C rows: j = jh + 4*g + reg.
  f32x4 bi[3], bh[3];
#pragma unroll
  for (int gt = 0; gt < 3; ++gt) {
    bi[gt] = *(const f32x4*)(bih + gt * 64 + jh + 4 * g);
    bh[gt] = *(const f32x4*)(bhh + gt * 64 + jh + 4 * g);
  }
  const f32x4 pqv = *(const f32x4*)(pq + (size_t)b * 64 + jh + 4 * g);
  const int len = lengths[b];

  f32x4 hreg = {0.f, 0.f, 0.f, 0.f};      // h for (b=c_clamped, j=jh+4g+reg)
  const float* xp = x + (size_t)b * Tq * 64 + g * 8;
  unsigned short* op = outbf + (size_t)b * 64 + jh + 4 * g;

  __syncthreads();

  for (int t = 0; t < Tq; ++t) {
    // x B-fragments (global, fp32 -> hi/lo)
    short8 xbH[2], xbL[2];
#pragma unroll
    for (int kc = 0; kc < 2; ++kc)
      split8(*(const f32x4*)(xp + kc * 32), *(const f32x4*)(xp + kc * 32 + 4),
             xbH[kc], xbL[kc]);

    // h B-fragments (LDS, already bf16 hi/lo — no conversion)
    short8 hbH[2], hbL[2];
#pragma unroll
    for (int kc = 0; kc < 2; ++kc) {
      hbH[kc] = *(const short8*)&hb_hi[t & 1][c][kc * 32 + g * 8];
      hbL[kc] = *(const short8*)&hb_lo[t & 1][c][kc * 32 + g * 8];
    }

    // Finalize previous step's scores (wave 0 only; slds double-buffered).
    if (t > 0 && w == 0 && lane < BT) {
      const int pb = (t - 1) & 1;
      float s = slds[pb][0][lane] + slds[pb][1][lane] + slds[pb][2][lane] + slds[pb][3][lane];
      scores[(size_t)(blockIdx.x * BT + lane) * Tq + (t - 1)] = s;
    }

    f32x4 gi[3], gh[3];
#pragma unroll
    for (int gt = 0; gt < 3; ++gt) { gi[gt] = bi[gt]; gh[gt] = bh[gt]; }
#pragma unroll
    for (int gt = 0; gt < 3; ++gt)
#pragma unroll
      for (int kc = 0; kc < 2; ++kc) {
        gi[gt] = MFMA(wiH[gt][kc], xbH[kc], gi[gt]);
        gi[gt] = MFMA(wiH[gt][kc], xbL[kc], gi[gt]);
        gi[gt] = MFMA(wiL[gt][kc], xbH[kc], gi[gt]);
        gh[gt] = MFMA(whH[gt][kc], hbH[kc], gh[gt]);
        gh[gt] = MFMA(whH[gt][kc], hbL[kc], gh[gt]);
        gh[gt] = MFMA(whL[gt][kc], hbH[kc], gh[gt]);
      }

    const bool valid = t < len;
    f32x4 outv;
#pragma unroll
    for (int r = 0; r < 4; ++r) {
      float rr = sigm(gi[0][r] + gh[0][r]);
      float zz = sigm(gi[1][r] + gh[1][r]);
      float nn = tanhf(gi[2][r] + rr * gh[2][r]);
      float hn = (1.f - zz) * nn + zz * hreg[r];
      hreg[r] = valid ? hn : hreg[r];
      outv[r] = valid ? hn : 0.f;     // padded steps emit 0 (pad_packed_sequence)
    }

    // Attention score partial: dot(pq[b], out[b, jslice]) -> reduce over j.
    float sp = outv[0] * pqv[0] + outv[1] * pqv[1] + outv[2] * pqv[2] + outv[3] * pqv[3];
    if (c >= BT) sp = 0.f;            // duplicate batch cols contribute nothing
    sp += __shfl_xor(sp, 16);
    sp += __shfl_xor(sp, 32);
    if (lane < BT) slds[t & 1][w][lane] = sp;

    // Write masked h (hi/lo bf16) into the other LDS buffer for step t+1.
    {
      unsigned short h0 = f2bf(hreg[0]), h1 = f2bf(hreg[1]);
      unsigned short h2 = f2bf(hreg[2]), h3 = f2bf(hreg[3]);
      unsigned short l0 = f2bf(hreg[0] - bf2f(h0)), l1 = f2bf(hreg[1] - bf2f(h1));
      unsigned short l2 = f2bf(hreg[2] - bf2f(h2)), l3 = f2bf(hreg[3] - bf2f(h3));
      uint2 H, L;
      H.x = (unsigned)h0 | ((unsigned)h1 << 16);
      H.y = (unsigned)h2 | ((unsigned)h3 << 16);
      L.x = (unsigned)l0 | ((unsigned)l1 << 16);
      L.y = (unsigned)l2 | ((unsigned)l3 << 16);
      *(uint2*)&hb_hi[(t + 1) & 1][c][jh + 4 * g] = H;
      *(uint2*)&hb_lo[(t + 1) & 1][c][jh + 4 * g] = L;
    }

    // Store out (bf16) for attention/AUGRU consumption.
    if (c < BT) {
      uint2 O;
      O.x = (unsigned)f2bf(outv[0]) | ((unsigned)f2bf(outv[1]) << 16);
      O.y = (unsigned)f2bf(outv[2]) | ((unsigned)f2bf(outv[3]) << 16);
      *(uint2*)op = O;
    }

    xp += 64;
    op += (size_t)Bq * 64;
    __syncthreads();
  }

  if (w == 0 && lane < BT) {
    const int pb = (Tq - 1) & 1;
    float s = slds[pb][0][lane] + slds[pb][1][lane] + slds[pb][2][lane] + slds[pb][3][lane];
    scores[(size_t)(blockIdx.x * BT + lane) * Tq + (Tq - 1)] = s;
  }
}

// ---------------------------------------------------------------------------
// Kernel 2: row softmax over scores (B rows of T=200). Wave per row.
// ---------------------------------------------------------------------------
__global__ __launch_bounds__(256)
void softmax_att(const float* __restrict__ scores, float* __restrict__ att)
{
  const int w = threadIdx.x >> 6, lane = threadIdx.x & 63;
  const int row = blockIdx.x * 4 + w;
  const float* s = scores + (size_t)row * Tq;
  float v0 = s[lane], v1 = s[lane + 64], v2 = s[lane + 128];
  float v3 = (lane < Tq - 192) ? s[lane + 192] : -1e30f;
  float m = fmaxf(fmaxf(v0, v1), fmaxf(v2, v3));
#pragma unroll
  for (int off = 32; off >= 1; off >>= 1) m = fmaxf(m, __shfl_xor(m, off));
  float e0 = __expf(v0 - m), e1 = __expf(v1 - m), e2 = __expf(v2 - m);
  float e3 = (lane < Tq - 192) ? __expf(v3 - m) : 0.f;
  float sum = e0 + e1 + e2 + e3;
#pragma unroll
  for (int off = 32; off >= 1; off >>= 1) sum += __shfl_xor(sum, off);
  float inv = 1.f / sum;
  float* a = att + (size_t)row * Tq;
  a[lane] = e0 * inv;
  a[lane + 64] = e1 * inv;
  a[lane + 128] = e2 * inv;
  if (lane < Tq - 192) a[lane + 192] = e3 * inv;
}

// ---------------------------------------------------------------------------
// Kernel 3: AUGRU. Same skeleton as GRU; input = bf16 `out` (B-frag lo term
// vanishes -> 12 gi MFMAs), update gate scaled by att; final h -> d_out.
// ---------------------------------------------------------------------------
__global__ __launch_bounds__(256, 2)
void augru_fwd(const unsigned short* __restrict__ outbf, const float* __restrict__ att,
               const int* __restrict__ lengths,
               const float* __restrict__ Wih, const float* __restrict__ Whh,
               const float* __restrict__ bih, const float* __restrict__ bhh,
               float* __restrict__ hout)
{
  __shared__ alignas(16) unsigned short hb_hi[2][16][72];
  __shared__ alignas(16) unsigned short hb_lo[2][16][72];

  const int tid  = threadIdx.x;
  const int w    = tid >> 6;
  const int lane = tid & 63;
  const int c    = lane & 15;
  const int g    = lane >> 4;
  const int bl   = c & (BT - 1);
  const int b    = blockIdx.x * BT + bl;
  const int jh   = w * 16;

  for (int i = tid; i < 2 * 16 * 72; i += 256) {
    ((unsigned short*)hb_hi)[i] = 0;
    ((unsigned short*)hb_lo)[i] = 0;
  }

  short8 wiH[3][2], wiL[3][2], whH[3][2], whL[3][2];
#pragma unroll
  for (int gt = 0; gt < 3; ++gt)
#pragma unroll
    for (int kc = 0; kc < 2; ++kc) {
      const float* p = Wih + (size_t)(gt * 64 + jh + c) * 64 + kc * 32 + g * 8;
      split8(*(const f32x4*)p, *(const f32x4*)(p + 4), wiH[gt][kc], wiL[gt][kc]);
      const float* q = Whh + (size_t)(gt * 64 + jh + c) * 64 + kc * 32 + g * 8;
      split8(*(const f32x4*)q, *(const f32x4*)(q + 4), whH[gt][kc], whL[gt][kc]);
    }

  f32x4 bi[3], bh[3];
#pragma unroll
  for (int gt = 0; gt < 3; ++gt) {
    bi[gt] = *(const f32x4*)(bih + gt * 64 + jh + 4 * g);
    bh[gt] = *(const f32x4*)(bhh + gt * 64 + jh + 4 * g);
  }
  const int len = lengths[b];
  const float* ap = att + (size_t)b * Tq;

  f32x4 hreg = {0.f, 0.f, 0.f, 0.f};
  const unsigned short* ip = outbf + (size_t)b * 64 + g * 8;

  __syncthreads();

  for (int t = 0; t < Tq; ++t) {
    short8 xb[2];
    xb[0] = *(const short8*)(ip);
    xb[1] = *(const short8*)(ip + 32);

    short8 hbH[2], hbL[2];
#pragma unroll
    for (int kc = 0; kc < 2; ++kc) {
      hbH[kc] = *(const short8*)&hb_hi[t & 1][c][kc * 32 + g * 8];
      hbL[kc] = *(const short8*)&hb_lo[t & 1][c][kc * 32 + g * 8];
    }
    const float a_t = ap[t];

    f32x4 gi[3], gh[3];
#pragma unroll
    for (int gt = 0; gt < 3; ++gt) { gi[gt] = bi[gt]; gh[gt] = bh[gt]; }
#pragma unroll
    for (int gt = 0; gt < 3; ++gt)
#pragma unroll
      for (int kc = 0; kc < 2; ++kc) {
        gi[gt] = MFMA(wiH[gt][kc], xb[kc], gi[gt]);
        gi[gt] = MFMA(wiL[gt][kc], xb[kc], gi[gt]);
        gh[gt] = MFMA(whH[gt][kc], hbH[kc], gh[gt]);
        gh[gt] = MFMA(whH[gt][kc], hbL[kc], gh[gt]);
        gh[gt] = MFMA(whL[gt][kc], hbH[kc], gh[gt]);
      }

    const bool valid = t < len;
#pragma unroll
    for (int r = 0; r < 4; ++r) {
      float rr = sigm(gi[0][r] + gh[0][r]);
      float uu = a_t * sigm(gi[1][r] + gh[1][r]);
      float nn = tanhf(gi[2][r] + rr * gh[2][r]);
      float hn = (1.f - uu) * hreg[r] + uu * nn;   // AUGRU blend orientation!
      hreg[r] = valid ? hn : hreg[r];
    }

    {
      unsigned short h0 = f2bf(hreg[0]), h1 = f2bf(hreg[1]);
      unsigned short h2 = f2bf(hreg[2]), h3 = f2bf(hreg[3]);
      unsigned short l0 = f2bf(hreg[0] - bf2f(h0)), l1 = f2bf(hreg[1] - bf2f(h1));
      unsigned short l2 = f2bf(hreg[2] - bf2f(h2)), l3 = f2bf(hreg[3] - bf2f(h3));
      uint2 H, L;
      H.x = (unsigned)h0 | ((unsigned)h1 << 16);
      H.y = (unsigned)h2 | ((unsigned)h3 << 16);
      L.x = (unsigned)l0 | ((unsigned)l1 << 16);
      L.y = (unsigned)l2 | ((unsigned)l3 << 16);
      *(uint2*)&hb_hi[(t + 1) & 1][c][jh + 4 * g] = H;
      *(uint2*)&hb_lo[(t + 1) & 1][c][jh + 4 * g] = L;
    }

    ip += (size_t)Bq * 64;
    __syncthreads();
  }

  if (c < BT)
    *(f32x4*)(hout + (size_t)b * 64 + jh + 4 * g) = hreg;
}

// ---------------------------------------------------------------------------
extern "C" void kernel_launch(void* const* d_in, const int* in_sizes, int n_in,
                              void* d_out, int out_size, void* d_ws, size_t ws_size,
                              hipStream_t stream)
{
  const float* x       = (const float*)d_in[0];
  const float* pq      = (const float*)d_in[1];
  const int*   lengths = (const int*)d_in[2];
  const float* Wih     = (const float*)d_in[3];
  const float* Whh     = (const float*)d_in[4];
  const float* bih     = (const float*)d_in[5];
  const float* bhh     = (const float*)d_in[6];
  const float* aWih    = (const float*)d_in[7];
  const float* aWhh    = (const float*)d_in[8];
  const float* abih    = (const float*)d_in[9];
  const float* abhh    = (const float*)d_in[10];
  float* hout = (float*)d_out;

  // Workspace layout: out bf16 [T][B][64] (104.8 MB) | scores [B][T] | att [B][T]
  char* ws = (char*)d_ws;
  unsigned short* outbf = (unsigned short*)ws;
  float* scores = (float*)(ws + (size_t)Tq * Bq * HIDq * 2);
  float* att    = scores + (size_t)Bq * Tq;

  gru_fwd<<<Bq / BT, 256, 0, stream>>>(x, pq, lengths, Wih, Whh, bih, bhh, outbf, scores);
  softmax_att<<<Bq / 4, 256, 0, stream>>>(scores, att);
  augru_fwd<<<Bq / BT, 256, 0, stream>>>(outbf, att, lengths, aWih, aWhh, abih, abhh, hout);
}

// Round 2
// 569.281 us; speedup vs baseline: 1.9128x; 1.9128x over previous
//
#include <hip/hip_runtime.h>

// ShortTermInterestExtractor — GRU(64->64, T=200, B=4096) + attention + AUGRU.
// R1: BT=16 (all MFMA cols), LDS-distributed x conversion, fast sigm/tanh,
//     AUGRU reads bf16 input frags directly from global with prefetch.

#define Bq   4096
#define Tq   200
#define BT   16

typedef __attribute__((ext_vector_type(8))) short short8;  // 8 bf16 (4 VGPRs)
typedef __attribute__((ext_vector_type(4))) float f32x4;

#define MFMA(a, b, c) __builtin_amdgcn_mfma_f32_16x16x32_bf16((a), (b), (c), 0, 0, 0)

static __device__ __forceinline__ unsigned short f2bf(float f) {  // RNE
  unsigned int u = __float_as_uint(f);
  u += 0x7fffu + ((u >> 16) & 1u);
  return (unsigned short)(u >> 16);
}
static __device__ __forceinline__ float bf2f(unsigned short h) {
  return __uint_as_float(((unsigned int)h) << 16);
}
static __device__ __forceinline__ float sigm(float x) {
  return __builtin_amdgcn_rcpf(1.0f + __expf(-x));
}
static __device__ __forceinline__ float tanh_(float x) {
  return 2.0f * __builtin_amdgcn_rcpf(1.0f + __expf(-2.0f * x)) - 1.0f;
}

static __device__ __forceinline__ void split8(f32x4 a, f32x4 b, short8 &hi, short8 &lo) {
#pragma unroll
  for (int i = 0; i < 4; ++i) {
    unsigned short h = f2bf(a[i]);
    hi[i] = (short)h;
    lo[i] = (short)f2bf(a[i] - bf2f(h));
  }
#pragma unroll
  for (int i = 0; i < 4; ++i) {
    unsigned short h = f2bf(b[i]);
    hi[i + 4] = (short)h;
    lo[i + 4] = (short)f2bf(b[i] - bf2f(h));
  }
}

static __device__ __forceinline__ void cvt4(f32x4 v, uint2 &H, uint2 &L) {
  unsigned short h0 = f2bf(v[0]), h1 = f2bf(v[1]), h2 = f2bf(v[2]), h3 = f2bf(v[3]);
  unsigned short l0 = f2bf(v[0] - bf2f(h0)), l1 = f2bf(v[1] - bf2f(h1));
  unsigned short l2 = f2bf(v[2] - bf2f(h2)), l3 = f2bf(v[3] - bf2f(h3));
  H.x = (unsigned)h0 | ((unsigned)h1 << 16);
  H.y = (unsigned)h2 | ((unsigned)h3 << 16);
  L.x = (unsigned)l0 | ((unsigned)l1 << 16);
  L.y = (unsigned)l2 | ((unsigned)l3 << 16);
}

// ---------------------------------------------------------------------------
// GRU + fused attention scores. 256 blocks x 256 thr (4 waves), 16 batch/block.
// Wave w owns hidden slice jh=16w. C layout (m89): col=lane&15 (=b),
// row=(lane>>4)*4+reg (=j). A/B frags: 16-dim = lane&15, k = (lane>>4)*8+e.
// ---------------------------------------------------------------------------
__global__ __launch_bounds__(256, 1)
void gru_fwd(const float* __restrict__ x, const float* __restrict__ pq,
             const int* __restrict__ lengths,
             const float* __restrict__ Wih, const float* __restrict__ Whh,
             const float* __restrict__ bih, const float* __restrict__ bhh,
             unsigned short* __restrict__ outbf,   // [T][B][64] bf16
             float* __restrict__ scores)           // [B][T] fp32
{
  __shared__ alignas(16) unsigned short hbH[2][16][72], hbL[2][16][72];
  __shared__ alignas(16) unsigned short xbH[2][16][72], xbL[2][16][72];
  __shared__ float slds[2][4][16];

  const int tid  = threadIdx.x;
  const int w    = tid >> 6;
  const int lane = tid & 63;
  const int c    = lane & 15;        // batch col / A row
  const int g    = lane >> 4;        // k-octet / C row group
  const int jh   = w * 16;
  const int b_g  = blockIdx.x * BT + c;

  // x staging map: thread -> (pb, pd) covering 16 b x 64 d, 4 floats each
  const int pb   = tid >> 4;
  const int pd   = 4 * (tid & 15);
  const int pb_g = blockIdx.x * BT + pb;

  for (int i = tid; i < 16 * 72; i += 256) {
    hbH[0][0][i] = 0; hbL[0][0][i] = 0;
  }
  {  // stage x(t=0)
    f32x4 xf = *(const f32x4*)(x + (size_t)pb_g * Tq * 64 + pd);
    uint2 H, L; cvt4(xf, H, L);
    *(uint2*)&xbH[0][pb][pd] = H;
    *(uint2*)&xbL[0][pb][pd] = L;
  }

  // Resident weight A-fragments (hi/lo): row m=c -> global row gate*64+jh+c.
  short8 wiH[3][2], wiL[3][2], whH[3][2], whL[3][2];
#pragma unroll
  for (int gt = 0; gt < 3; ++gt)
#pragma unroll
    for (int kc = 0; kc < 2; ++kc) {
      const float* p = Wih + (size_t)(gt * 64 + jh + c) * 64 + kc * 32 + g * 8;
      split8(*(const f32x4*)p, *(const f32x4*)(p + 4), wiH[gt][kc], wiL[gt][kc]);
      const float* q = Whh + (size_t)(gt * 64 + jh + c) * 64 + kc * 32 + g * 8;
      split8(*(const f32x4*)q, *(const f32x4*)(q + 4), whH[gt][kc], whL[gt][kc]);
    }

  // Biases along C rows j = jh+4g+r; r,z merged (gi+gh), n split.
  f32x4 bR, bZ, bNi, bNh;
  {
    f32x4 bi0 = *(const f32x4*)(bih + 0 * 64 + jh + 4 * g);
    f32x4 bh0 = *(const f32x4*)(bhh + 0 * 64 + jh + 4 * g);
    f32x4 bi1 = *(const f32x4*)(bih + 1 * 64 + jh + 4 * g);
    f32x4 bh1 = *(const f32x4*)(bhh + 1 * 64 + jh + 4 * g);
    bR = bi0 + bh0; bZ = bi1 + bh1;
    bNi = *(const f32x4*)(bih + 2 * 64 + jh + 4 * g);
    bNh = *(const f32x4*)(bhh + 2 * 64 + jh + 4 * g);
  }
  const f32x4 pqv = *(const f32x4*)(pq + (size_t)b_g * 64 + jh + 4 * g);
  const int len = lengths[b_g];

  f32x4 hreg = {0.f, 0.f, 0.f, 0.f};
  __syncthreads();

  for (int t = 0; t < Tq; ++t) {
    const int cur = t & 1, nxt = cur ^ 1;

    // prefetch x(t+1)
    f32x4 xf = {0.f, 0.f, 0.f, 0.f};
    if (t + 1 < Tq)
      xf = *(const f32x4*)(x + (size_t)pb_g * Tq * 64 + (size_t)(t + 1) * 64 + pd);

    // fragments
    short8 xH[2], xL[2], hH[2], hL[2];
#pragma unroll
    for (int kc = 0; kc < 2; ++kc) {
      xH[kc] = *(const short8*)&xbH[cur][c][kc * 32 + g * 8];
      xL[kc] = *(const short8*)&xbL[cur][c][kc * 32 + g * 8];
      hH[kc] = *(const short8*)&hbH[cur][c][kc * 32 + g * 8];
      hL[kc] = *(const short8*)&hbL[cur][c][kc * 32 + g * 8];
    }

    // finalize previous step's scores (wave 0)
    if (t > 0 && w == 0 && lane < 16) {
      float s = slds[nxt][0][lane] + slds[nxt][1][lane] +
                slds[nxt][2][lane] + slds[nxt][3][lane];
      scores[(size_t)(blockIdx.x * BT + lane) * Tq + (t - 1)] = s;
    }

    f32x4 aR = bR, aZ = bZ, aNi = bNi, aNh = bNh;
#pragma unroll
    for (int kc = 0; kc < 2; ++kc) {
      aR = MFMA(wiH[0][kc], xH[kc], aR);
      aR = MFMA(wiH[0][kc], xL[kc], aR);
      aR = MFMA(wiL[0][kc], xH[kc], aR);
      aR = MFMA(whH[0][kc], hH[kc], aR);
      aR = MFMA(whH[0][kc], hL[kc], aR);
      aR = MFMA(whL[0][kc], hH[kc], aR);
      aZ = MFMA(wiH[1][kc], xH[kc], aZ);
      aZ = MFMA(wiH[1][kc], xL[kc], aZ);
      aZ = MFMA(wiL[1][kc], xH[kc], aZ);
      aZ = MFMA(whH[1][kc], hH[kc], aZ);
      aZ = MFMA(whH[1][kc], hL[kc], aZ);
      aZ = MFMA(whL[1][kc], hH[kc], aZ);
      aNi = MFMA(wiH[2][kc], xH[kc], aNi);
      aNi = MFMA(wiH[2][kc], xL[kc], aNi);
      aNi = MFMA(wiL[2][kc], xH[kc], aNi);
      aNh = MFMA(whH[2][kc], hH[kc], aNh);
      aNh = MFMA(whH[2][kc], hL[kc], aNh);
      aNh = MFMA(whL[2][kc], hH[kc], aNh);
    }

    const bool valid = t < len;
    f32x4 outv;
#pragma unroll
    for (int r = 0; r < 4; ++r) {
      float rr = sigm(aR[r]);
      float zz = sigm(aZ[r]);
      float nn = tanh_(aNi[r] + rr * aNh[r]);
      float hn = (1.f - zz) * nn + zz * hreg[r];
      hreg[r] = valid ? hn : hreg[r];
      outv[r] = valid ? hn : 0.f;
    }

    // attention score partial, reduce over j (g groups, then waves via slds)
    float sp = outv[0] * pqv[0] + outv[1] * pqv[1] + outv[2] * pqv[2] + outv[3] * pqv[3];
    sp += __shfl_xor(sp, 16);
    sp += __shfl_xor(sp, 32);
    if (lane < 16) slds[cur][w][lane] = sp;

    // h (masked) -> LDS hi/lo for step t+1
    {
      uint2 H, L; cvt4(hreg, H, L);
      *(uint2*)&hbH[nxt][c][jh + 4 * g] = H;
      *(uint2*)&hbL[nxt][c][jh + 4 * g] = L;
    }

    // out store (bf16)
    {
      uint2 O;
      O.x = (unsigned)f2bf(outv[0]) | ((unsigned)f2bf(outv[1]) << 16);
      O.y = (unsigned)f2bf(outv[2]) | ((unsigned)f2bf(outv[3]) << 16);
      *(uint2*)(outbf + (size_t)t * Bq * 64 + (size_t)b_g * 64 + jh + 4 * g) = O;
    }

    // stage x(t+1)
    {
      uint2 H, L; cvt4(xf, H, L);
      *(uint2*)&xbH[nxt][pb][pd] = H;
      *(uint2*)&xbL[nxt][pb][pd] = L;
    }

    __syncthreads();
  }

  if (w == 0 && lane < 16) {
    const int pb2 = (Tq - 1) & 1;
    float s = slds[pb2][0][lane] + slds[pb2][1][lane] +
              slds[pb2][2][lane] + slds[pb2][3][lane];
    scores[(size_t)(blockIdx.x * BT + lane) * Tq + (Tq - 1)] = s;
  }
}

// ---------------------------------------------------------------------------
// Row softmax over scores (B rows of T=200). Wave per row.
// ---------------------------------------------------------------------------
__global__ __launch_bounds__(256)
void softmax_att(const float* __restrict__ scores, float* __restrict__ att)
{
  const int w = threadIdx.x >> 6, lane = threadIdx.x & 63;
  const int row = blockIdx.x * 4 + w;
  const float* s = scores + (size_t)row * Tq;
  float v0 = s[lane], v1 = s[lane + 64], v2 = s[lane + 128];
  float v3 = (lane < Tq - 192) ? s[lane + 192] : -1e30f;
  float m = fmaxf(fmaxf(v0, v1), fmaxf(v2, v3));
#pragma unroll
  for (int off = 32; off >= 1; off >>= 1) m = fmaxf(m, __shfl_xor(m, off));
  float e0 = __expf(v0 - m), e1 = __expf(v1 - m), e2 = __expf(v2 - m);
  float e3 = (lane < Tq - 192) ? __expf(v3 - m) : 0.f;
  float sum = e0 + e1 + e2 + e3;
#pragma unroll
  for (int off = 32; off >= 1; off >>= 1) sum += __shfl_xor(sum, off);
  float inv = 1.f / sum;
  float* a = att + (size_t)row * Tq;
  a[lane] = e0 * inv;
  a[lane + 64] = e1 * inv;
  a[lane + 128] = e2 * inv;
  if (lane < Tq - 192) a[lane + 192] = e3 * inv;
}

// ---------------------------------------------------------------------------
// AUGRU. Input = bf16 `out` read directly from global as B-frags (prefetched).
// ---------------------------------------------------------------------------
__global__ __launch_bounds__(256, 1)
void augru_fwd(const unsigned short* __restrict__ outbf, const float* __restrict__ att,
               const int* __restrict__ lengths,
               const float* __restrict__ Wih, const float* __restrict__ Whh,
               const float* __restrict__ bih, const float* __restrict__ bhh,
               float* __restrict__ hout)
{
  __shared__ alignas(16) unsigned short hbH[2][16][72], hbL[2][16][72];
  __shared__ float att_lds[16][204];   // padded stride vs bank aliasing

  const int tid  = threadIdx.x;
  const int w    = tid >> 6;
  const int lane = tid & 63;
  const int c    = lane & 15;
  const int g    = lane >> 4;
  const int jh   = w * 16;
  const int b_g  = blockIdx.x * BT + c;

  for (int i = tid; i < 16 * 72; i += 256) {
    hbH[0][0][i] = 0; hbL[0][0][i] = 0;
  }
  for (int i = tid; i < BT * Tq; i += 256)
    att_lds[i / Tq][i % Tq] = att[(size_t)blockIdx.x * BT * Tq + i];

  short8 wiH[3][2], wiL[3][2], whH[3][2], whL[3][2];
#pragma unroll
  for (int gt = 0; gt < 3; ++gt)
#pragma unroll
    for (int kc = 0; kc < 2; ++kc) {
      const float* p = Wih + (size_t)(gt * 64 + jh + c) * 64 + kc * 32 + g * 8;
      split8(*(const f32x4*)p, *(const f32x4*)(p + 4), wiH[gt][kc], wiL[gt][kc]);
      const float* q = Whh + (size_t)(gt * 64 + jh + c) * 64 + kc * 32 + g * 8;
      split8(*(const f32x4*)q, *(const f32x4*)(q + 4), whH[gt][kc], whL[gt][kc]);
    }

  f32x4 bR, bZ, bNi, bNh;
  {
    f32x4 bi0 = *(const f32x4*)(bih + 0 * 64 + jh + 4 * g);
    f32x4 bh0 = *(const f32x4*)(bhh + 0 * 64 + jh + 4 * g);
    f32x4 bi1 = *(const f32x4*)(bih + 1 * 64 + jh + 4 * g);
    f32x4 bh1 = *(const f32x4*)(bhh + 1 * 64 + jh + 4 * g);
    bR = bi0 + bh0; bZ = bi1 + bh1;
    bNi = *(const f32x4*)(bih + 2 * 64 + jh + 4 * g);
    bNh = *(const f32x4*)(bhh + 2 * 64 + jh + 4 * g);
  }
  const int len = lengths[b_g];

  // input frags for t=0 direct from global (layout [T][B][64] == B-frag layout)
  short8 xcur[2];
#pragma unroll
  for (int kc = 0; kc < 2; ++kc)
    xcur[kc] = *(const short8*)(outbf + (size_t)b_g * 64 + kc * 32 + g * 8);

  f32x4 hreg = {0.f, 0.f, 0.f, 0.f};
  __syncthreads();

  for (int t = 0; t < Tq; ++t) {
    const int cur = t & 1, nxt = cur ^ 1;

    short8 xnxt[2];
    if (t + 1 < Tq) {
#pragma unroll
      for (int kc = 0; kc < 2; ++kc)
        xnxt[kc] = *(const short8*)(outbf + (size_t)(t + 1) * Bq * 64 +
                                    (size_t)b_g * 64 + kc * 32 + g * 8);
    } else {
      xnxt[0] = xcur[0]; xnxt[1] = xcur[1];
    }

    short8 hH[2], hL[2];
#pragma unroll
    for (int kc = 0; kc < 2; ++kc) {
      hH[kc] = *(const short8*)&hbH[cur][c][kc * 32 + g * 8];
      hL[kc] = *(const short8*)&hbL[cur][c][kc * 32 + g * 8];
    }
    const float a_t = att_lds[c][t];

    f32x4 aR = bR, aZ = bZ, aNi = bNi, aNh = bNh;
#pragma unroll
    for (int kc = 0; kc < 2; ++kc) {
      aR = MFMA(wiH[0][kc], xcur[kc], aR);
      aR = MFMA(wiL[0][kc], xcur[kc], aR);
      aR = MFMA(whH[0][kc], hH[kc], aR);
      aR = MFMA(whH[0][kc], hL[kc], aR);
      aR = MFMA(whL[0][kc], hH[kc], aR);
      aZ = MFMA(wiH[1][kc], xcur[kc], aZ);
      aZ = MFMA(wiL[1][kc], xcur[kc], aZ);
      aZ = MFMA(whH[1][kc], hH[kc], aZ);
      aZ = MFMA(whH[1][kc], hL[kc], aZ);
      aZ = MFMA(whL[1][kc], hH[kc], aZ);
      aNi = MFMA(wiH[2][kc], xcur[kc], aNi);
      aNi = MFMA(wiL[2][kc], xcur[kc], aNi);
      aNh = MFMA(whH[2][kc], hH[kc], aNh);
      aNh = MFMA(whH[2][kc], hL[kc], aNh);
      aNh = MFMA(whL[2][kc], hH[kc], aNh);
    }

    const bool valid = t < len;
#pragma unroll
    for (int r = 0; r < 4; ++r) {
      float rr = sigm(aR[r]);
      float uu = a_t * sigm(aZ[r]);
      float nn = tanh_(aNi[r] + rr * aNh[r]);
      float hn = (1.f - uu) * hreg[r] + uu * nn;   // AUGRU blend orientation
      hreg[r] = valid ? hn : hreg[r];
    }

    {
      uint2 H, L; cvt4(hreg, H, L);
      *(uint2*)&hbH[nxt][c][jh + 4 * g] = H;
      *(uint2*)&hbL[nxt][c][jh + 4 * g] = L;
    }

    xcur[0] = xnxt[0]; xcur[1] = xnxt[1];
    __syncthreads();
  }

  *(f32x4*)(hout + (size_t)b_g * 64 + jh + 4 * g) = hreg;
}

// ---------------------------------------------------------------------------
extern "C" void kernel_launch(void* const* d_in, const int* in_sizes, int n_in,
                              void* d_out, int out_size, void* d_ws, size_t ws_size,
                              hipStream_t stream)
{
  const float* x       = (const float*)d_in[0];
  const float* pq      = (const float*)d_in[1];
  const int*   lengths = (const int*)d_in[2];
  const float* Wih     = (const float*)d_in[3];
  const float* Whh     = (const float*)d_in[4];
  const float* bih     = (const float*)d_in[5];
  const float* bhh     = (const float*)d_in[6];
  const float* aWih    = (const float*)d_in[7];
  const float* aWhh    = (const float*)d_in[8];
  const float* abih    = (const float*)d_in[9];
  const float* abhh    = (const float*)d_in[10];
  float* hout = (float*)d_out;

  // ws: out bf16 [T][B][64] (104.8 MB) | scores [B][T] | att [B][T]
  char* ws = (char*)d_ws;
  unsigned short* outbf = (unsigned short*)ws;
  float* scores = (float*)(ws + (size_t)Tq * Bq * 64 * 2);
  float* att    = scores + (size_t)Bq * Tq;

  gru_fwd<<<Bq / BT, 256, 0, stream>>>(x, pq, lengths, Wih, Whh, bih, bhh, outbf, scores);
  softmax_att<<<Bq / 4, 256, 0, stream>>>(scores, att);
  augru_fwd<<<Bq / BT, 256, 0, stream>>>(outbf, att, lengths, aWih, aWhh, abih, abhh, hout);
}